// Round 10
// baseline (371.998 us; speedup 1.0000x reference)
//
#include <hip/hip_runtime.h>
#include <hip/hip_bf16.h>
#include <math.h>

// Problem constants
#define T_LEN 2048
#define C_DIM 2048
#define NH 16
#define HD 128
#define RANK 64
#define W_LOCAL 512
#define QKV_LD 6144
#define ROW_BF 12288          // qkv row stride in bf16 elems
#define KB_OFF 4096           // bf16-elem offset of packed K overlay within row
#define VB_OFF 8192           // bf16-elem offset of packed V overlay within row
#define WO_OFF 6144           // bf16-elem offset of packed w_o row within qkv row
#define XLO_OFF 10240         // bf16-elem offset of x_lo row within qkv row (free chunk)
#define SCALE 0.08838834764831845f    // 1/sqrt(128)
#define SCALE_G 0.17677669529663687f  // scale * 128/64
#define LOG1E4_OVER_64 0.14391156831212787f

typedef __bf16 bf16_t;
typedef __bf16 bf16x8 __attribute__((ext_vector_type(8)));
typedef __bf16 bf16x4 __attribute__((ext_vector_type(4)));
typedef float f32x4 __attribute__((ext_vector_type(4)));

// ---------------------------------------------------------------------------
// async 16B global -> LDS (gfx950). LDS dst must be wave-uniform base+lane*16.
// ---------------------------------------------------------------------------
__device__ __forceinline__ void async_copy16(const bf16_t* g, bf16_t* l) {
    __builtin_amdgcn_global_load_lds(
        (const __attribute__((address_space(1))) unsigned int*)g,
        (__attribute__((address_space(3))) unsigned int*)l, 16, 0, 0);
}

__device__ __forceinline__ float gelu_exact(float v) {
    return 0.5f * v * (1.0f + erff(v * 0.70710678118654752f));
}

// ---------------------------------------------------------------------------
// Merged prep kernel (block-range dispatch):
//  [0,2048):    x -> xb (contig) + xlo (per-qkv-row free chunk, stride ROW_BF)
//  [2048,2560): w1 -> (w1hi contig, w1lo contig)
//  [2560,8704): w_qkv -> wqb bf16
//  [8704,9216): rope tables
// ---------------------------------------------------------------------------
__global__ __launch_bounds__(256)
void prep_kernel(const float* __restrict__ x, bf16_t* __restrict__ xb,
                 bf16_t* __restrict__ qkvb_xlo,
                 const float* __restrict__ w1, bf16_t* __restrict__ w1hi,
                 bf16_t* __restrict__ w1lo,
                 const float* __restrict__ w_qkv, bf16_t* __restrict__ wqb,
                 float* __restrict__ tab) {
    const int bid = blockIdx.x;
    const int tid = threadIdx.x;
    if (bid < 2048) {
        // x split: row = idx>>8 (256 chunks of 8 per row), c = (idx&255)*8
        int idx = bid * 256 + tid;
        int row = idx >> 8, c = (idx & 255) << 3;
        const float* p = x + (size_t)row * 2048 + c;
        float4 v0 = *(const float4*)p;
        float4 v1 = *(const float4*)(p + 4);
        float v[8] = {v0.x, v0.y, v0.z, v0.w, v1.x, v1.y, v1.z, v1.w};
        bf16x8 h, l;
#pragma unroll
        for (int i = 0; i < 8; ++i) {
            bf16_t hb = (bf16_t)v[i];
            h[i] = hb;
            l[i] = (bf16_t)(v[i] - (float)hb);
        }
        *(bf16x8*)(xb + (size_t)row * 2048 + c) = h;
        *(bf16x8*)(qkvb_xlo + (size_t)row * ROW_BF + XLO_OFF + c) = l;
    } else if (bid < 2560) {
        // w1 split (contig, 512x2048)
        int idx = (bid - 2048) * 256 + tid;
        const float* p = w1 + (size_t)idx * 8;
        float4 v0 = *(const float4*)p;
        float4 v1 = *(const float4*)(p + 4);
        float v[8] = {v0.x, v0.y, v0.z, v0.w, v1.x, v1.y, v1.z, v1.w};
        bf16x8 h, l;
#pragma unroll
        for (int i = 0; i < 8; ++i) {
            bf16_t hb = (bf16_t)v[i];
            h[i] = hb;
            l[i] = (bf16_t)(v[i] - (float)hb);
        }
        *(bf16x8*)(w1hi + (size_t)idx * 8) = h;
        *(bf16x8*)(w1lo + (size_t)idx * 8) = l;
    } else if (bid < 8704) {
        int idx = (bid - 2560) * 256 + tid;
        const float* p = w_qkv + (size_t)idx * 8;
        float4 v0 = *(const float4*)p;
        float4 v1 = *(const float4*)(p + 4);
        bf16x8 o;
        o[0] = (bf16_t)v0.x; o[1] = (bf16_t)v0.y; o[2] = (bf16_t)v0.z; o[3] = (bf16_t)v0.w;
        o[4] = (bf16_t)v1.x; o[5] = (bf16_t)v1.y; o[6] = (bf16_t)v1.z; o[7] = (bf16_t)v1.w;
        *(bf16x8*)(wqb + (size_t)idx * 8) = o;
    } else {
        int idx = (bid - 8704) * 256 + tid;
        int t = idx >> 6, j = idx & 63;
        float inv = expf(-(float)j * LOG1E4_OVER_64);
        float s, c;
        sincosf((float)t * inv, &s, &c);
        tab[t * 128 + j] = c;
        tab[t * 128 + 64 + j] = s;
    }
}

// ---------------------------------------------------------------------------
// bf16 MFMA GEMM (m97 recipe) — final out = ctx @ w_o^T
// ---------------------------------------------------------------------------
#define GBK 32

__global__ __launch_bounds__(256)
void gemm_bf16_nt(const bf16_t* __restrict__ A, const bf16_t* __restrict__ B,
                  float* __restrict__ C, int K, int lda, int ldb, int ldc) {
    __shared__ bf16_t As[128 * GBK];
    __shared__ bf16_t Bs[128 * GBK];
    const int tid = threadIdx.x;
    const int wave = tid >> 6, lane = tid & 63;
    const int quad = lane >> 4, l16 = lane & 15;
    const int bm = blockIdx.y * 128, bn = blockIdx.x * 128;
    const int wm = (wave >> 1) * 64, wn = (wave & 1) * 64;
    const int lrow = lane >> 2;
    const int lkb = (lane & 3) * 8;

    f32x4 acc[4][4];
#pragma unroll
    for (int i = 0; i < 4; ++i)
#pragma unroll
        for (int j = 0; j < 4; ++j) acc[i][j] = (f32x4){0.f, 0.f, 0.f, 0.f};

    const bf16_t* gA = A + (size_t)(bm + wave * 16 + lrow) * lda + lkb;
    const bf16_t* gB = B + (size_t)(bn + wave * 16 + lrow) * ldb + lkb;
    bf16_t* lA = &As[(wave * 16 + lrow) * GBK + lkb];
    bf16_t* lB = &Bs[(wave * 16 + lrow) * GBK + lkb];

    for (int k0 = 0; k0 < K; k0 += GBK) {
        __syncthreads();
        async_copy16(gA + k0, lA);
        async_copy16(gA + (size_t)64 * lda + k0, lA + 64 * GBK);
        async_copy16(gB + k0, lB);
        async_copy16(gB + (size_t)64 * ldb + k0, lB + 64 * GBK);
        __syncthreads();

        bf16x8 a[4], b[4];
#pragma unroll
        for (int mt = 0; mt < 4; ++mt)
            a[mt] = *(const bf16x8*)&As[(wm + mt * 16 + l16) * GBK + quad * 8];
#pragma unroll
        for (int nt = 0; nt < 4; ++nt)
            b[nt] = *(const bf16x8*)&Bs[(wn + nt * 16 + l16) * GBK + quad * 8];
#pragma unroll
        for (int mt = 0; mt < 4; ++mt)
#pragma unroll
            for (int nt = 0; nt < 4; ++nt)
                acc[mt][nt] = __builtin_amdgcn_mfma_f32_16x16x32_bf16(a[mt], b[nt], acc[mt][nt], 0, 0, 0);
    }

#pragma unroll
    for (int mt = 0; mt < 4; ++mt)
#pragma unroll
        for (int r = 0; r < 4; ++r) {
            int row = bm + wm + mt * 16 + quad * 4 + r;
            float* crow = C + (size_t)row * ldc + bn + wn;
#pragma unroll
            for (int nt = 0; nt < 4; ++nt)
                crow[nt * 16 + l16] = acc[mt][nt][r];
        }
}

// ---------------------------------------------------------------------------
// MEGA launch: qkv GEMM (+RoPE epilogue) || info MLP GEMM || w_o conversion.
//  [0,768):     qkv GEMM blocks (bm=(id/48)*128, bn=(id%48)*128)
//  [768,896):   info split-K=2 blocks (bx=l&3, by=(l>>2)&15, ks=l>>6)
//  [896,2944):  w_o row conversions
// info partials -> Cpart (in d_out). xlo lives in qkv-row free chunks
// (disjoint from all epilogue writes; 128B-aligned boundary).
// ---------------------------------------------------------------------------
__global__ __launch_bounds__(256)
void mega_kernel(const bf16_t* __restrict__ A, const bf16_t* __restrict__ B,
                 float* __restrict__ qkv, bf16_t* __restrict__ qkv_bf,
                 const float* __restrict__ tab, const float* __restrict__ w_o,
                 const bf16_t* __restrict__ w1hi, const bf16_t* __restrict__ w1lo,
                 float* __restrict__ Cpart) {
    __shared__ bf16_t smem[4 * 128 * GBK];   // 32 KB union
    const int bid = blockIdx.x;
    const int tid = threadIdx.x;

    if (bid >= 896) {
        // ---- w_o conversion: one row per block ----
        int row = bid - 896;
        int c = tid * 8;
        const float* p = w_o + (size_t)row * 2048 + c;
        float4 v0 = *(const float4*)p;
        float4 v1 = *(const float4*)(p + 4);
        bf16x8 o;
        o[0] = (bf16_t)v0.x; o[1] = (bf16_t)v0.y; o[2] = (bf16_t)v0.z; o[3] = (bf16_t)v0.w;
        o[4] = (bf16_t)v1.x; o[5] = (bf16_t)v1.y; o[6] = (bf16_t)v1.z; o[7] = (bf16_t)v1.w;
        *(bf16x8*)(qkv_bf + (size_t)row * ROW_BF + WO_OFF + c) = o;
        return;
    }

    const int wave = tid >> 6, lane = tid & 63;
    const int quad = lane >> 4, l16 = lane & 15;
    const int wm = (wave >> 1) * 64, wn = (wave & 1) * 64;
    const int lrow = lane >> 2;
    const int lkb = (lane & 3) * 8;

    if (bid >= 768) {
        // ---- info MLP GEMM: hi*hi + hi*lo + lo*hi, split-K=2 ----
        bf16_t* Ah = smem;
        bf16_t* Al = smem + 128 * GBK;
        bf16_t* Bh = smem + 2 * 128 * GBK;
        bf16_t* Bl = smem + 3 * 128 * GBK;
        const int l = bid - 768;
        const int bm = ((l >> 2) & 15) * 128, bn = (l & 3) * 128;
        const int ks = l >> 6;
        const int kbeg = ks * 1024;

        f32x4 acc[4][4];
#pragma unroll
        for (int i = 0; i < 4; ++i)
#pragma unroll
            for (int j = 0; j < 4; ++j) acc[i][j] = (f32x4){0.f, 0.f, 0.f, 0.f};

        const int arow = bm + wave * 16 + lrow;
        const size_t ahio = (size_t)arow * 2048 + lkb + kbeg;           // xb (lda 2048)
        const size_t aloo = (size_t)arow * ROW_BF + XLO_OFF + lkb + kbeg; // xlo (lda ROW_BF)
        const size_t boff = (size_t)(bn + wave * 16 + lrow) * 2048 + lkb + kbeg;
        bf16_t* lAh = &Ah[(wave * 16 + lrow) * GBK + lkb];
        bf16_t* lAl = &Al[(wave * 16 + lrow) * GBK + lkb];
        bf16_t* lBh = &Bh[(wave * 16 + lrow) * GBK + lkb];
        bf16_t* lBl = &Bl[(wave * 16 + lrow) * GBK + lkb];

        for (int k0 = 0; k0 < 1024; k0 += GBK) {
            __syncthreads();
            async_copy16(A + ahio + k0, lAh);
            async_copy16(A + ahio + (size_t)64 * 2048 + k0, lAh + 64 * GBK);
            async_copy16(qkv_bf + aloo + k0, lAl);
            async_copy16(qkv_bf + aloo + (size_t)64 * ROW_BF + k0, lAl + 64 * GBK);
            async_copy16(w1hi + boff + k0, lBh);
            async_copy16(w1hi + boff + (size_t)64 * 2048 + k0, lBh + 64 * GBK);
            async_copy16(w1lo + boff + k0, lBl);
            async_copy16(w1lo + boff + (size_t)64 * 2048 + k0, lBl + 64 * GBK);
            __syncthreads();

            bf16x8 ah[4], al[4], bh[4], bl[4];
#pragma unroll
            for (int mt = 0; mt < 4; ++mt) {
                ah[mt] = *(const bf16x8*)&Ah[(wm + mt * 16 + l16) * GBK + quad * 8];
                al[mt] = *(const bf16x8*)&Al[(wm + mt * 16 + l16) * GBK + quad * 8];
            }
#pragma unroll
            for (int nt = 0; nt < 4; ++nt) {
                bh[nt] = *(const bf16x8*)&Bh[(wn + nt * 16 + l16) * GBK + quad * 8];
                bl[nt] = *(const bf16x8*)&Bl[(wn + nt * 16 + l16) * GBK + quad * 8];
            }
#pragma unroll
            for (int mt = 0; mt < 4; ++mt)
#pragma unroll
                for (int nt = 0; nt < 4; ++nt) {
                    acc[mt][nt] = __builtin_amdgcn_mfma_f32_16x16x32_bf16(ah[mt], bh[nt], acc[mt][nt], 0, 0, 0);
                    acc[mt][nt] = __builtin_amdgcn_mfma_f32_16x16x32_bf16(ah[mt], bl[nt], acc[mt][nt], 0, 0, 0);
                    acc[mt][nt] = __builtin_amdgcn_mfma_f32_16x16x32_bf16(al[mt], bh[nt], acc[mt][nt], 0, 0, 0);
                }
        }

        float* cp = Cpart + (size_t)ks * 2048 * 512;
#pragma unroll
        for (int mt = 0; mt < 4; ++mt)
#pragma unroll
            for (int r = 0; r < 4; ++r) {
                int row = bm + wm + mt * 16 + quad * 4 + r;
                float* crow = cp + (size_t)row * 512 + bn + wn;
#pragma unroll
                for (int nt = 0; nt < 4; ++nt)
                    crow[nt * 16 + l16] = acc[mt][nt][r];
            }
        return;
    }

    // ---- qkv GEMM + RoPE epilogue ----
    bf16_t* As = smem;
    bf16_t* Bs = smem + 128 * GBK;
    const int bm = (bid / 48) * 128, bn = (bid % 48) * 128;

    f32x4 acc[4][4];
#pragma unroll
    for (int i = 0; i < 4; ++i)
#pragma unroll
        for (int j = 0; j < 4; ++j) acc[i][j] = (f32x4){0.f, 0.f, 0.f, 0.f};

    const bf16_t* gA = A + (size_t)(bm + wave * 16 + lrow) * 2048 + lkb;
    const bf16_t* gB = B + (size_t)(bn + wave * 16 + lrow) * 2048 + lkb;
    bf16_t* lA = &As[(wave * 16 + lrow) * GBK + lkb];
    bf16_t* lB = &Bs[(wave * 16 + lrow) * GBK + lkb];

    for (int k0 = 0; k0 < 2048; k0 += GBK) {
        __syncthreads();
        async_copy16(gA + k0, lA);
        async_copy16(gA + (size_t)64 * 2048 + k0, lA + 64 * GBK);
        async_copy16(gB + k0, lB);
        async_copy16(gB + (size_t)64 * 2048 + k0, lB + 64 * GBK);
        __syncthreads();

        bf16x8 a[4], b[4];
#pragma unroll
        for (int mt = 0; mt < 4; ++mt)
            a[mt] = *(const bf16x8*)&As[(wm + mt * 16 + l16) * GBK + quad * 8];
#pragma unroll
        for (int nt = 0; nt < 4; ++nt)
            b[nt] = *(const bf16x8*)&Bs[(wn + nt * 16 + l16) * GBK + quad * 8];
#pragma unroll
        for (int mt = 0; mt < 4; ++mt)
#pragma unroll
            for (int nt = 0; nt < 4; ++nt)
                acc[mt][nt] = __builtin_amdgcn_mfma_f32_16x16x32_bf16(a[mt], b[nt], acc[mt][nt], 0, 0, 0);
    }

    const int colbase = bn + wn;
    const int region = colbase >> 11;       // 0=q, 1=k, 2=v
    const bool odd = (l16 & 1);

    if (region == 2) {
#pragma unroll
        for (int mt = 0; mt < 4; ++mt)
#pragma unroll
            for (int r = 0; r < 4; ++r) {
                int t = bm + wm + mt * 16 + quad * 4 + r;
                bf16_t* brow = qkv_bf + (size_t)t * ROW_BF + VB_OFF + (colbase - 4096);
#pragma unroll
                for (int nt = 0; nt < 4; ++nt)
                    brow[nt * 16 + l16] = (bf16_t)acc[mt][nt][r];
            }
    } else {
#pragma unroll
        for (int mt = 0; mt < 4; ++mt)
#pragma unroll
            for (int r = 0; r < 4; ++r) {
                int t = bm + wm + mt * 16 + quad * 4 + r;
                const float* trow = tab + t * 128;
#pragma unroll
                for (int nt = 0; nt < 4; ++nt) {
                    float v = acc[mt][nt][r];
                    float vp = __shfl_xor(v, 1);
                    int col = colbase + nt * 16 + l16;
                    int j = col & 63;
                    float c = trow[j], s = trow[64 + j];
                    float y = odd ? (v * c + vp * s) : (v * c - vp * s);
                    if (region == 0)
                        qkv[(size_t)t * QKV_LD + col] = y;
                    else
                        qkv_bf[(size_t)t * ROW_BF + KB_OFF + (col - 2048)] = (bf16_t)y;
                }
            }
    }
}

// ---------------------------------------------------------------------------
// kvr (blocks [0,512)) + info-gate (blocks [512,1024), 4 tokens via 4 waves)
// ---------------------------------------------------------------------------
#define KV_LD 136

__global__ __launch_bounds__(256)
void kvr_gate_kernel(const float* __restrict__ qkv, const bf16_t* __restrict__ qkv_bf,
                     const float* __restrict__ pk, const float* __restrict__ pv,
                     float* __restrict__ kr, float* __restrict__ vr,
                     bf16_t* __restrict__ qr,
                     const float* __restrict__ Cpart, const float* __restrict__ w2,
                     float* __restrict__ gate) {
    __shared__ bf16_t Kt[64 * KV_LD];
    __shared__ bf16_t Vt[64 * KV_LD];
    __shared__ bf16_t Qt[64 * KV_LD];
    __shared__ bf16_t Pk[64 * KV_LD];
    __shared__ bf16_t Pv[64 * KV_LD];

    const int bid = blockIdx.x;
    const int tid = threadIdx.x;
    const int wave = tid >> 6, lane = tid & 63;

    if (bid >= 512) {
        // ---- gate: token per wave; fixed fp32 order (deterministic) ----
        int t = (bid - 512) * 4 + wave;
        const float* p0 = Cpart + (size_t)t * 512;
        float s = 0.f;
#pragma unroll
        for (int i = lane; i < 512; i += 64) {
            float v = p0[i] + p0[i + 1048576];
            s += gelu_exact(v) * w2[i];
        }
#pragma unroll
        for (int off = 32; off > 0; off >>= 1) s += __shfl_down(s, off);
        if (lane == 0) {
            float sig = 1.f / (1.f + expf(-s));
            gate[t] = (sig > 0.75f) ? 1.f : 0.f;
        }
        return;
    }

    const int h = bid >> 5;
    const int s0 = (bid & 31) * 64;
    const int quad = lane >> 4, l16 = lane & 15;

#pragma unroll
    for (int i = 0; i < 4; ++i) {
        int gid = i * 256 + tid;
        int row = gid >> 4, ch = (gid & 15) << 3;
        const bf16_t* rb = qkv_bf + (size_t)(s0 + row) * ROW_BF + h * HD + ch;
        *(bf16x8*)&Kt[row * KV_LD + ch] = *(const bf16x8*)(rb + KB_OFF);
        *(bf16x8*)&Vt[row * KV_LD + ch] = *(const bf16x8*)(rb + VB_OFF);
    }
#pragma unroll
    for (int i = 0; i < 8; ++i) {
        int gid = i * 256 + tid;
        int row = gid >> 5, c = (gid & 31) << 2;
        float4 vq = *(const float4*)(qkv + (size_t)(s0 + row) * QKV_LD + h * HD + c);
        bf16x4 pq;
        pq[0] = (bf16_t)vq.x; pq[1] = (bf16_t)vq.y; pq[2] = (bf16_t)vq.z; pq[3] = (bf16_t)vq.w;
        *(bf16x4*)&Qt[row * KV_LD + c] = pq;
        float4 wk = *(const float4*)(pk + (size_t)row * HD + c);
        float4 wv = *(const float4*)(pv + (size_t)row * HD + c);
        bf16x4 qk4, qv4;
        qk4[0] = (bf16_t)wk.x; qk4[1] = (bf16_t)wk.y; qk4[2] = (bf16_t)wk.z; qk4[3] = (bf16_t)wk.w;
        qv4[0] = (bf16_t)wv.x; qv4[1] = (bf16_t)wv.y; qv4[2] = (bf16_t)wv.z; qv4[3] = (bf16_t)wv.w;
        *(bf16x4*)&Pk[row * KV_LD + c] = qk4;
        *(bf16x4*)&Pv[row * KV_LD + c] = qv4;
    }
    __syncthreads();

    f32x4 ak[4], av[4], aq[4];
#pragma unroll
    for (int nt = 0; nt < 4; ++nt) {
        ak[nt] = (f32x4){0.f, 0.f, 0.f, 0.f};
        av[nt] = (f32x4){0.f, 0.f, 0.f, 0.f};
        aq[nt] = (f32x4){0.f, 0.f, 0.f, 0.f};
    }

#pragma unroll
    for (int ks = 0; ks < 4; ++ks) {
        const int ao = (wave * 16 + l16) * KV_LD + ks * 32 + quad * 8;
        bf16x8 a_k = *(const bf16x8*)&Kt[ao];
        bf16x8 a_v = *(const bf16x8*)&Vt[ao];
        bf16x8 a_q = *(const bf16x8*)&Qt[ao];
#pragma unroll
        for (int nt = 0; nt < 4; ++nt) {
            const int bo = (nt * 16 + l16) * KV_LD + ks * 32 + quad * 8;
            bf16x8 bk = *(const bf16x8*)&Pk[bo];
            bf16x8 bv = *(const bf16x8*)&Pv[bo];
            ak[nt] = __builtin_amdgcn_mfma_f32_16x16x32_bf16(a_k, bk, ak[nt], 0, 0, 0);
            av[nt] = __builtin_amdgcn_mfma_f32_16x16x32_bf16(a_v, bv, av[nt], 0, 0, 0);
            aq[nt] = __builtin_amdgcn_mfma_f32_16x16x32_bf16(a_q, bk, aq[nt], 0, 0, 0);
        }
    }

#pragma unroll
    for (int nt = 0; nt < 4; ++nt)
#pragma unroll
        for (int r = 0; r < 4; ++r) {
            int s = s0 + wave * 16 + quad * 4 + r;
            size_t idx = ((size_t)h * T_LEN + s) * RANK + nt * 16 + l16;
            kr[idx] = ak[nt][r];
            vr[idx] = av[nt][r];
            qr[idx] = (bf16_t)aq[nt][r];
        }
}

// ---------------------------------------------------------------------------
// MFMA bf16 flash local attention (v2 + mask elision, unchanged from R9)
// ---------------------------------------------------------------------------
#define QTI 64
#define KTI 64
#define QS_LD 136
#define VT_LD 68
#define PS_LD 72

__global__ __launch_bounds__(256)
void local_attn_kernel(const float* __restrict__ qkv, const bf16_t* __restrict__ qkv_bf,
                       bf16_t* __restrict__ cxb) {
    __shared__ bf16_t Qs[QTI * QS_LD];
    __shared__ bf16_t Ks[KTI * HD];
    __shared__ bf16_t Vt[HD * VT_LD];
    __shared__ bf16_t Ps[4][16 * PS_LD];

    const int h = blockIdx.y;
    const int t0 = blockIdx.x * QTI;
    const int tid = threadIdx.x;
    const int wave = tid >> 6, lane = tid & 63;
    const int quad = lane >> 4, l16 = lane & 15;

#pragma unroll
    for (int i = 0; i < 8; ++i) {
        int gid = i * 256 + tid;
        int row = gid >> 5, c4 = (gid & 31) << 2;
        const float4 v = *(const float4*)(qkv + (size_t)(t0 + row) * QKV_LD + h * HD + c4);
        bf16x4 p;
        p[0] = (bf16_t)(v.x * SCALE); p[1] = (bf16_t)(v.y * SCALE);
        p[2] = (bf16_t)(v.z * SCALE); p[3] = (bf16_t)(v.w * SCALE);
        *(bf16x4*)&Qs[row * QS_LD + c4] = p;
    }

    f32x4 o[8];
#pragma unroll
    for (int d8 = 0; d8 < 8; ++d8) o[d8] = (f32x4){0.f, 0.f, 0.f, 0.f};
    float m_i[4] = {-1e30f, -1e30f, -1e30f, -1e30f};
    float l_i[4] = {0.f, 0.f, 0.f, 0.f};

    __syncthreads();

    for (int kt = 0; kt < 9; ++kt) {
        const int sbase = t0 - 512 + kt * KTI;
        if (sbase < 0) continue;
        __syncthreads();
#pragma unroll
        for (int i = 0; i < 4; ++i) {
            int s = i * 256 + tid;
            int row = s >> 4, ch = s & 15;
            int gch = ch ^ (row & 7);
            const bf16_t* src = qkv_bf + (size_t)(sbase + row) * ROW_BF + KB_OFF + h * HD + gch * 8;
            async_copy16(src, &Ks[s * 8]);
        }
#pragma unroll
        for (int i = 0; i < 8; ++i) {
            int gid = i * 256 + tid;
            int row = gid >> 5, c4 = (gid & 31) << 2;
            bf16x4 vv = *(const bf16x4*)(qkv_bf + (size_t)(sbase + row) * ROW_BF + VB_OFF + h * HD + c4);
            Vt[(c4 + 0) * VT_LD + row] = vv[0];
            Vt[(c4 + 1) * VT_LD + row] = vv[1];
            Vt[(c4 + 2) * VT_LD + row] = vv[2];
            Vt[(c4 + 3) * VT_LD + row] = vv[3];
        }
        __syncthreads();

        f32x4 sacc[4];
#pragma unroll
        for (int nt = 0; nt < 4; ++nt) sacc[nt] = (f32x4){0.f, 0.f, 0.f, 0.f};
#pragma unroll
        for (int ks = 0; ks < 4; ++ks) {
            bf16x8 a = *(const bf16x8*)&Qs[(wave * 16 + l16) * QS_LD + ks * 32 + quad * 8];
#pragma unroll
            for (int nt = 0; nt < 4; ++nt) {
                int r = nt * 16 + l16;
                int ch = (ks * 4 + quad) ^ (r & 7);
                bf16x8 b = *(const bf16x8*)&Ks[r * HD + ch * 8];
                sacc[nt] = __builtin_amdgcn_mfma_f32_16x16x32_bf16(a, b, sacc[nt], 0, 0, 0);
            }
        }

        if (kt == 0 || kt == 8) {
#pragma unroll
            for (int nt = 0; nt < 4; ++nt) {
                int s_g = sbase + nt * 16 + l16;
#pragma unroll
                for (int r = 0; r < 4; ++r) {
                    int t_g = t0 + wave * 16 + quad * 4 + r;
                    bool valid = (s_g <= t_g) && (s_g + W_LOCAL > t_g);
                    if (!valid) sacc[nt][r] = -1e30f;
                }
            }
        }

#pragma unroll
        for (int r = 0; r < 4; ++r) {
            float mx = fmaxf(fmaxf(sacc[0][r], sacc[1][r]), fmaxf(sacc[2][r], sacc[3][r]));
            mx = fmaxf(mx, __shfl_xor(mx, 1));
            mx = fmaxf(mx, __shfl_xor(mx, 2));
            mx = fmaxf(mx, __shfl_xor(mx, 4));
            mx = fmaxf(mx, __shfl_xor(mx, 8));
            float mnew = fmaxf(m_i[r], mx);
            float alpha = __expf(m_i[r] - mnew);
            m_i[r] = mnew;
            float rs = 0.f;
#pragma unroll
            for (int nt = 0; nt < 4; ++nt) {
                float p = __expf(sacc[nt][r] - mnew);
                sacc[nt][r] = p;
                rs += p;
            }
            rs += __shfl_xor(rs, 1);
            rs += __shfl_xor(rs, 2);
            rs += __shfl_xor(rs, 4);
            rs += __shfl_xor(rs, 8);
            l_i[r] = l_i[r] * alpha + rs;
#pragma unroll
            for (int d8 = 0; d8 < 8; ++d8) o[d8][r] *= alpha;
        }

#pragma unroll
        for (int r = 0; r < 4; ++r)
#pragma unroll
            for (int nt = 0; nt < 4; ++nt)
                Ps[wave][(quad * 4 + r) * PS_LD + nt * 16 + l16] = (bf16_t)sacc[nt][r];

#pragma unroll
        for (int ks2 = 0; ks2 < 2; ++ks2) {
            bf16x8 a = *(const bf16x8*)&Ps[wave][l16 * PS_LD + ks2 * 32 + quad * 8];
#pragma unroll
            for (int d8 = 0; d8 < 8; ++d8) {
                const bf16_t* vb = &Vt[(d8 * 16 + l16) * VT_LD + ks2 * 32 + quad * 8];
                bf16x4 b0 = *(const bf16x4*)vb;
                bf16x4 b1 = *(const bf16x4*)(vb + 4);
                bf16x8 b;
                b[0] = b0[0]; b[1] = b0[1]; b[2] = b0[2]; b[3] = b0[3];
                b[4] = b1[0]; b[5] = b1[1]; b[6] = b1[2]; b[7] = b1[3];
                o[d8] = __builtin_amdgcn_mfma_f32_16x16x32_bf16(a, b, o[d8], 0, 0, 0);
            }
        }
    }

#pragma unroll
    for (int r = 0; r < 4; ++r) {
        float inv = 1.0f / l_i[r];
        size_t rowoff = (size_t)(t0 + wave * 16 + quad * 4 + r) * 2048 + h * HD;
#pragma unroll
        for (int d8 = 0; d8 < 8; ++d8)
            cxb[rowoff + d8 * 16 + l16] = (bf16_t)(o[d8][r] * inv);
    }
}

// ---------------------------------------------------------------------------
// Gated global low-rank branch (early-exit when gate==0); bf16 RMW into cxb
// ---------------------------------------------------------------------------
__device__ __forceinline__ float block_reduce_max512(float v, float* red, int tid) {
    red[tid] = v; __syncthreads();
    for (int s = 256; s > 0; s >>= 1) {
        if (tid < s) red[tid] = fmaxf(red[tid], red[tid + s]);
        __syncthreads();
    }
    float r = red[0]; __syncthreads();
    return r;
}
__device__ __forceinline__ float block_reduce_sum512(float v, float* red, int tid) {
    red[tid] = v; __syncthreads();
    for (int s = 256; s > 0; s >>= 1) {
        if (tid < s) red[tid] = red[tid] + red[tid + s];
        __syncthreads();
    }
    float r = red[0]; __syncthreads();
    return r;
}

__global__ __launch_bounds__(512)
void global_attn_kernel(bf16_t* __restrict__ cxb, const float* __restrict__ kr,
                        const float* __restrict__ vr, const bf16_t* __restrict__ qr,
                        const float* __restrict__ uo, const float* __restrict__ gate) {
    const int t = blockIdx.x, h = blockIdx.y;
    if (gate[t] <= 0.5f) return;

    __shared__ float qrs[64];
    __shared__ float red[512];
    __shared__ float cgr[64];
    __shared__ float sg[2048];
    const int tid = threadIdx.x;

    if (tid < 64) qrs[tid] = (float)qr[((size_t)h * T_LEN + t) * RANK + tid];
    __syncthreads();

    const float* krh = kr + (size_t)h * T_LEN * RANK;
    const float* vrh = vr + (size_t)h * T_LEN * RANK;
    float lmax = -INFINITY;
    for (int s = tid; s < T_LEN; s += 512) {
        const float* krr = krh + (size_t)s * RANK;
        float acc = 0.f;
#pragma unroll
        for (int r = 0; r < RANK; r += 4) {
            float4 k4 = *(const float4*)(krr + r);
            acc += qrs[r] * k4.x + qrs[r + 1] * k4.y + qrs[r + 2] * k4.z + qrs[r + 3] * k4.w;
        }
        float sc = acc * SCALE_G;
        sg[s] = sc;
        lmax = fmaxf(lmax, sc);
    }
    float gmx = block_reduce_max512(lmax, red, tid);
    float lsum = 0.f;
    for (int s = tid; s < T_LEN; s += 512) {
        float pp = expf(sg[s] - gmx);
        sg[s] = pp;
        lsum += pp;
    }
    float gsum = block_reduce_sum512(lsum, red, tid);

    {
        const int r = tid & 63, part = tid >> 6;
        float pacc = 0.f;
        for (int s = part; s < T_LEN; s += 8) pacc += sg[s] * vrh[(size_t)s * RANK + r];
        red[tid] = pacc;
        __syncthreads();
        if (tid < 64) {
            float c = 0.f;
#pragma unroll
            for (int pp = 0; pp < 8; ++pp) c += red[pp * 64 + tid];
            cgr[tid] = c / gsum;
        }
        __syncthreads();
    }

    if (tid < 128) {
        float cg = 0.f;
#pragma unroll
        for (int r = 0; r < RANK; ++r) cg += cgr[r] * uo[tid * RANK + r];
        size_t off = (size_t)t * 2048 + h * HD + tid;
        cxb[off] = (bf16_t)((float)cxb[off] + cg);
    }
}

// ---------------------------------------------------------------------------
extern "C" void kernel_launch(void* const* d_in, const int* in_sizes, int n_in,
                              void* d_out, int out_size, void* d_ws, size_t ws_size,
                              hipStream_t stream) {
    const float* x     = (const float*)d_in[0];
    const float* w_qkv = (const float*)d_in[1];
    const float* w_o   = (const float*)d_in[2];
    const float* pk    = (const float*)d_in[3];
    const float* pv    = (const float*)d_in[4];
    const float* uo    = (const float*)d_in[5];
    const float* w1    = (const float*)d_in[6];
    const float* w2    = (const float*)d_in[7];
    float* out = (float*)d_out;

    // Workspace layout (floats), lifetime-aliased (~84 MB):
    float* ws = (float*)d_ws;
    float* qkv   = ws;                        // rows: q fp32 | K bf16 | wo bf16 | V bf16 | xlo bf16
    float* hinfo = qkv + (size_t)12582912;    // [0,262144): rope tab; [262144,786432): w1hi; later qr
    float* gatep = hinfo + (size_t)1048576;   // 2048 f
    bf16_t* xb   = (bf16_t*)(gatep + 2048);   // x_hi bf16 (later ctx bf16)
    float* wqbf  = gatep + 2048 + 2097152;    // 6,291,456 f: wqb, later kr/vr
    bf16_t* wqb  = (bf16_t*)wqbf;
    float* krp   = wqbf;
    float* vrp   = wqbf + (size_t)2097152;
    float* tabp  = hinfo;                     // rope tables
    bf16_t* w1hi = (bf16_t*)(hinfo + 262144); // 1,048,576 bf16
    bf16_t* qrp  = (bf16_t*)hinfo;            // qr bf16 (kvr launch; tab/w1hi dead)
    bf16_t* cxb  = xb;                        // ctx bf16
    bf16_t* qkvb = (bf16_t*)qkv;              // bf16 overlay view
    bf16_t* wob  = qkvb + WO_OFF;             // w_o bf16 inside qkv rows
    // d_out doubles as info scratch (overwritten by final GEMM):
    float* ipart = out;                       // 2x2048x512 f = [0, 2097152)
    bf16_t* w1lo = (bf16_t*)(out + 2097152);  // 1,048,576 bf16 = [2097152, 2621440) f

    // 1) prep: x->(xb, xlo-in-qkv-rows), w1->(w1hi,w1lo), w_qkv->bf16, tables
    prep_kernel<<<9216, 256, 0, stream>>>(x, xb, qkvb, w1, w1hi, w1lo, w_qkv, wqb, tabp);
    // 2) MEGA: qkv GEMM+RoPE || info MLP GEMM (->d_out) || w_o conversion
    mega_kernel<<<2944, 256, 0, stream>>>(xb, wqb, qkv, qkvb, tabp, w_o, w1hi, w1lo, ipart);
    // 3) kvr (kr/vr/qr) || info-gate (reads d_out partials)
    kvr_gate_kernel<<<1024, 256, 0, stream>>>(qkv, qkvb, pk, pv, krp, vrp, qrp,
                                              ipart, w2, gatep);
    // 4) flash local attention -> ctx bf16
    local_attn_kernel<<<dim3(T_LEN / QTI, NH), 256, 0, stream>>>(qkv, qkvb, cxb);
    // 5) gated global branch (bf16 RMW into cxb)
    global_attn_kernel<<<dim3(T_LEN, NH), 512, 0, stream>>>(cxb, krp, vrp, qrp, uo, gatep);
    // 6) out = ctx @ w_o^T (overwrites info scratch in d_out)
    gemm_bf16_nt<<<dim3(16, 16), 256, 0, stream>>>(cxb, wob, out, 2048, 2048, ROW_BF, 2048);
}